// Round 1
// baseline (467.876 us; speedup 1.0000x reference)
//
#include <hip/hip_runtime.h>

// Problem sizes (fixed)
#define NB   32
#define CI   256
#define HH   56
#define WW   56
#define PL   128   // planes (conv1/conv2 out channels)
#define HO   28
#define WO   28
#define CO   512   // out_planes

typedef unsigned long long u64;

// ---------------- K0: pack weight signs ----------------
// w1d[ci*128+co]  = +-1.0 (f64) of W1[co,ci]
// wscd[ci*512+co] = +-1.0 (f64) of Wsc[co,ci]
// w2b[(co*9+tap)*2 + word] : bit ci set iff W2[co,ci,kh,kw] >= 0
// w3b[co*2 + word]         : bit ci set iff W3[co,ci] >= 0
__global__ __launch_bounds__(256) void pack_kernel(
    const float* __restrict__ W1, const float* __restrict__ W2,
    const float* __restrict__ W3, const float* __restrict__ Wsc,
    double* __restrict__ w1d, double* __restrict__ wscd,
    u64* __restrict__ w2b, u64* __restrict__ w3b) {
  int tid = blockIdx.x * 256 + threadIdx.x;
  if (tid < 32768) {
    int co = tid & 127, ci = tid >> 7;
    w1d[tid] = (W1[co * 256 + ci] >= 0.f) ? 1.0 : -1.0;
  } else if (tid < 32768 + 131072) {
    int i = tid - 32768;
    int co = i & 511, ci = i >> 9;
    wscd[i] = (Wsc[co * 256 + ci] >= 0.f) ? 1.0 : -1.0;
  } else if (tid < 32768 + 131072 + 1152) {
    int i = tid - (32768 + 131072);   // co*9 + tap
    int co = i / 9, tap = i % 9;
    u64 b0 = 0, b1v = 0;
    for (int ci = 0; ci < 128; ++ci) {
      if (W2[(co * 128 + ci) * 9 + tap] >= 0.f) {
        if (ci < 64) b0 |= 1ull << ci; else b1v |= 1ull << (ci - 64);
      }
    }
    w2b[i * 2] = b0; w2b[i * 2 + 1] = b1v;
  } else if (tid < 32768 + 131072 + 1152 + 512) {
    int co = tid - (32768 + 131072 + 1152);
    u64 b0 = 0, b1v = 0;
    for (int ci = 0; ci < 128; ++ci) {
      if (W3[co * 128 + ci] >= 0.f) {
        if (ci < 64) b0 |= 1ull << ci; else b1v |= 1ull << (ci - 64);
      }
    }
    w3b[co * 2] = b0; w3b[co * 2 + 1] = b1v;
  }
}

// ---------------- K1: conv1 (1x1, f64 exact) + bn1 + sign -> a1 bitmask ----
// block = (n,h) row; 256 threads; thread: co0 = 4*(t&31), w0 = 7*(t>>5)
// a1b[((n*56+h)*56+w)*2 + half] : 128-bit activation mask (bit c = channel c)
__global__ __launch_bounds__(256) void conv1_kernel(
    const float* __restrict__ x, const double* __restrict__ w1d,
    const float* __restrict__ g1, const float* __restrict__ b1,
    const float* __restrict__ m1, const float* __restrict__ v1,
    u64* __restrict__ a1b) {
  __shared__ float4 xrow4[CI * WW / 4];           // 57344 B
  __shared__ unsigned char pk[WW * 32];           // nibble staging
  float* xrow = (float*)xrow4;

  int bid = blockIdx.x;
  int n = bid / HH, h = bid % HH;
  int t = threadIdx.x;

  const float4* xsrc = (const float4*)(x + (size_t)n * CI * (HH * WW) + h * WW);
  // 3584 float4 to stage; row stride in float4 = 3136/4 = 784
  for (int i = 0; i < 14; ++i) {
    int idx = i * 256 + t;
    int ci = idx / 14, f = idx % 14;
    xrow4[ci * 14 + f] = xsrc[(size_t)ci * 784 + f];
  }
  __syncthreads();

  int cg = t & 31, wg = t >> 5;
  int co0 = cg * 4, w0 = wg * 7;
  double acc[4][7];
  for (int c = 0; c < 4; ++c)
    for (int j = 0; j < 7; ++j) acc[c][j] = 0.0;

  const double* wp = w1d + co0;
  for (int ci = 0; ci < 256; ++ci) {
    double2 wA = *(const double2*)(wp + ci * 128);
    double2 wB = *(const double2*)(wp + ci * 128 + 2);
    const float* xr = xrow + ci * WW + w0;
#pragma unroll
    for (int j = 0; j < 7; ++j) {
      double xd = (double)xr[j];
      acc[0][j] = fma(wA.x, xd, acc[0][j]);
      acc[1][j] = fma(wA.y, xd, acc[1][j]);
      acc[2][j] = fma(wB.x, xd, acc[2][j]);
      acc[3][j] = fma(wB.y, xd, acc[3][j]);
    }
  }

  double sv[4], mv[4], bv[4];
  for (int c = 0; c < 4; ++c) {
    int co = co0 + c;
    double inv = 1.0 / sqrt((double)v1[co] + 1e-5);
    sv[c] = (double)g1[co] * inv;
    mv[c] = (double)m1[co];
    bv[c] = (double)b1[co];
  }
  for (int j = 0; j < 7; ++j) {
    unsigned nib = 0;
    for (int c = 0; c < 4; ++c) {
      double val = (acc[c][j] - mv[c]) * sv[c] + bv[c];
      if (val >= 0.0) nib |= 1u << c;
    }
    pk[(w0 + j) * 32 + cg] = (unsigned char)nib;
  }
  __syncthreads();

  if (t < 112) {
    int w = t >> 1, half = t & 1;
    u64 word = 0;
    for (int k = 0; k < 16; ++k)
      word |= ((u64)pk[w * 32 + half * 16 + k]) << (4 * k);
    a1b[((size_t)(n * HH + h) * WW + w) * 2 + half] = word;
  }
}

// ---------------- K2: conv2 (3x3 s2 p1, XNOR-popcount) + bn2 + sign --------
// block = 4 positions (1 per wave); lane owns co = lane and co = lane+64
__global__ __launch_bounds__(256) void conv2_kernel(
    const u64* __restrict__ a1b, const u64* __restrict__ w2b,
    const float* __restrict__ g2, const float* __restrict__ b2,
    const float* __restrict__ m2, const float* __restrict__ v2,
    u64* __restrict__ a2b) {
  __shared__ u64 lw2[128 * 9 * 2];   // 18432 B
  int t = threadIdx.x;
  for (int k = 0; k < 9; ++k) lw2[t * 9 + k] = w2b[t * 9 + k];
  __syncthreads();

  int p = blockIdx.x * 4 + (t >> 6);    // 0..25087
  int lane = t & 63;
  int n = p / (HO * WO), r = p % (HO * WO);
  int ho = r / WO, wo = r % WO;

  int y0 = 0, y1 = 0;
  for (int kh = 0; kh < 3; ++kh) {
    int ih = 2 * ho - 1 + kh;
    if (ih < 0) continue;
    for (int kw = 0; kw < 3; ++kw) {
      int iw = 2 * wo - 1 + kw;
      if (iw < 0) continue;
      const u64* ap = a1b + ((size_t)(n * HH + ih) * WW + iw) * 2;
      u64 a0 = ap[0], a1v = ap[1];
      int tap = kh * 3 + kw;
      u64 wa = lw2[lane * 18 + tap * 2], wb = lw2[lane * 18 + tap * 2 + 1];
      y0 += 128 - 2 * (__popcll(a0 ^ wa) + __popcll(a1v ^ wb));
      wa = lw2[(lane + 64) * 18 + tap * 2]; wb = lw2[(lane + 64) * 18 + tap * 2 + 1];
      y1 += 128 - 2 * (__popcll(a0 ^ wa) + __popcll(a1v ^ wb));
    }
  }

  int co = lane;
  double inv = 1.0 / sqrt((double)v2[co] + 1e-5);
  bool c0 = (((double)y0 - (double)m2[co]) * ((double)g2[co] * inv) + (double)b2[co]) >= 0.0;
  co = lane + 64;
  inv = 1.0 / sqrt((double)v2[co] + 1e-5);
  bool c1 = (((double)y1 - (double)m2[co]) * ((double)g2[co] * inv) + (double)b2[co]) >= 0.0;

  u64 word0 = __ballot(c0);
  u64 word1 = __ballot(c1);
  if (lane == 0) {
    a2b[(size_t)p * 2] = word0;
    a2b[(size_t)p * 2 + 1] = word1;
  }
}

// ---------------- K3: shortcut conv (f64) + conv3 (popcount) + bns + sign --
// block = (n,ho); 512 threads; thread: co0 = 4*(t&127), w0 = 7*(t>>7)
__global__ __launch_bounds__(512) void conv3_sc_kernel(
    const float* __restrict__ x, const double* __restrict__ wscd,
    const u64* __restrict__ a2b, const u64* __restrict__ w3b,
    const float* __restrict__ g3, const float* __restrict__ b3,
    const float* __restrict__ m3, const float* __restrict__ v3,
    const float* __restrict__ gs, const float* __restrict__ bs,
    const float* __restrict__ ms, const float* __restrict__ vs,
    float* __restrict__ out) {
  __shared__ float4 xrow4[CI * WW / 4];     // 57344 B (full rows h = 2*ho)
  __shared__ u64 a2row[WO * 2];
  float* xrow = (float*)xrow4;

  int bid = blockIdx.x;
  int n = bid / HO, ho = bid % HO;
  int t = threadIdx.x;

  const float4* xsrc = (const float4*)(x + (size_t)n * CI * (HH * WW) + (2 * ho) * WW);
  for (int i = 0; i < 7; ++i) {
    int idx = i * 512 + t;
    int ci = idx / 14, f = idx % 14;
    xrow4[ci * 14 + f] = xsrc[(size_t)ci * 784 + f];
  }
  if (t < 56)
    a2row[t] = a2b[((size_t)(n * HO + ho) * WO + (t >> 1)) * 2 + (t & 1)];
  __syncthreads();

  int cg = t & 127, wg = t >> 7;
  int co0 = cg * 4, w0 = wg * 7;
  double acc[4][7];
  for (int c = 0; c < 4; ++c)
    for (int j = 0; j < 7; ++j) acc[c][j] = 0.0;

  const double* wp = wscd + co0;
  for (int ci = 0; ci < 256; ++ci) {
    double2 wA = *(const double2*)(wp + ci * 512);
    double2 wB = *(const double2*)(wp + ci * 512 + 2);
    const float* xr = xrow + ci * WW + 2 * w0;
#pragma unroll
    for (int j = 0; j < 7; ++j) {
      double xd = (double)xr[2 * j];
      acc[0][j] = fma(wA.x, xd, acc[0][j]);
      acc[1][j] = fma(wA.y, xd, acc[1][j]);
      acc[2][j] = fma(wB.x, xd, acc[2][j]);
      acc[3][j] = fma(wB.y, xd, acc[3][j]);
    }
  }

  for (int c = 0; c < 4; ++c) {
    int co = co0 + c;
    double invs = 1.0 / sqrt((double)vs[co] + 1e-5);
    double ssc = (double)gs[co] * invs;
    double msd = (double)ms[co], bsd = (double)bs[co];
    double inv3 = 1.0 / sqrt((double)v3[co] + 1e-5);
    double s3 = (double)g3[co] * inv3;
    double m3d = (double)m3[co], b3d = (double)b3[co];
    u64 w30 = w3b[co * 2], w31 = w3b[co * 2 + 1];
    float* op = out + ((size_t)(n * CO + co) * HO + ho) * WO + w0;
    for (int j = 0; j < 7; ++j) {
      int wo = w0 + j;
      u64 a0 = a2row[wo * 2], a1v = a2row[wo * 2 + 1];
      int y3 = 128 - 2 * (__popcll(a0 ^ w30) + __popcll(a1v ^ w31));
      double val = (acc[c][j] - msd) * ssc + bsd +
                   (((double)y3 - m3d) * s3 + b3d);
      op[j] = (val >= 0.0) ? 1.0f : -1.0f;
    }
  }
}

extern "C" void kernel_launch(void* const* d_in, const int* in_sizes, int n_in,
                              void* d_out, int out_size, void* d_ws, size_t ws_size,
                              hipStream_t stream) {
  const float* x   = (const float*)d_in[0];
  const float* W1  = (const float*)d_in[1];
  const float* W2  = (const float*)d_in[2];
  const float* W3  = (const float*)d_in[3];
  const float* Wsc = (const float*)d_in[4];
  const float* g1 = (const float*)d_in[5],  *b1 = (const float*)d_in[6];
  const float* m1 = (const float*)d_in[7],  *v1 = (const float*)d_in[8];
  const float* g2 = (const float*)d_in[9],  *b2 = (const float*)d_in[10];
  const float* m2 = (const float*)d_in[11], *v2 = (const float*)d_in[12];
  const float* g3 = (const float*)d_in[13], *b3 = (const float*)d_in[14];
  const float* m3 = (const float*)d_in[15], *v3 = (const float*)d_in[16];
  const float* gs = (const float*)d_in[17], *bs = (const float*)d_in[18];
  const float* ms = (const float*)d_in[19], *vs = (const float*)d_in[20];

  char* ws = (char*)d_ws;
  double* w1d  = (double*)(ws + 0);          // 262144 B
  double* wscd = (double*)(ws + 262144);     // 1048576 B
  u64*    a1b  = (u64*)(ws + 1310720);       // 1605632 B
  u64*    a2b  = (u64*)(ws + 2916352);       // 401408 B
  u64*    w2b  = (u64*)(ws + 3317760);       // 18432 B
  u64*    w3b  = (u64*)(ws + 3336192);       // 8192 B
  float* out = (float*)d_out;

  hipLaunchKernelGGL(pack_kernel, dim3(647), dim3(256), 0, stream,
                     W1, W2, W3, Wsc, w1d, wscd, w2b, w3b);
  hipLaunchKernelGGL(conv1_kernel, dim3(NB * HH), dim3(256), 0, stream,
                     x, w1d, g1, b1, m1, v1, a1b);
  hipLaunchKernelGGL(conv2_kernel, dim3(NB * HO * WO / 4), dim3(256), 0, stream,
                     a1b, w2b, g2, b2, m2, v2, a2b);
  hipLaunchKernelGGL(conv3_sc_kernel, dim3(NB * HO), dim3(512), 0, stream,
                     x, wscd, a2b, w3b, g3, b3, m3, v3, gs, bs, ms, vs, out);
}